// Round 4
// baseline (194.707 us; speedup 1.0000x reference)
//
#include <hip/hip_runtime.h>
#include <hip/hip_bf16.h>

#define EMB    512
#define HEAD   64
#define SEQ    4096
#define NB     4
#define NSPLIT 8
#define LDX    72   // padded LDS row stride (144 B, 16B-aligned)

#define SL2E   0.18033688011112042f   // (1/sqrt(64)) * log2(e), folded into Wq

typedef __bf16 bf16x8 __attribute__((ext_vector_type(8)));
typedef float  f32x4  __attribute__((ext_vector_type(4)));

__device__ inline ushort4 cvt4(float4 v) {
    __hip_bfloat16 a = __float2bfloat16(v.x), b = __float2bfloat16(v.y);
    __hip_bfloat16 c = __float2bfloat16(v.z), d = __float2bfloat16(v.w);
    ushort4 r;
    r.x = *(unsigned short*)&a; r.y = *(unsigned short*)&b;
    r.z = *(unsigned short*)&c; r.w = *(unsigned short*)&d;
    return r;
}

// ---------------------------------------------------------------------------
// One-shot W convert: [3][64][512] fp32 -> bf16; Wq pre-scaled by SL2E.
// ---------------------------------------------------------------------------
__global__ __launch_bounds__(256) void cvtw_kernel(
    const float* __restrict__ Wq, const float* __restrict__ Wk,
    const float* __restrict__ Wv, __hip_bfloat16* __restrict__ Wc)
{
    int idx   = blockIdx.x * 256 + threadIdx.x;
    int which = idx >> 13;
    int off   = (idx & 8191) * 4;
    const float* src = (which == 0) ? Wq : (which == 1) ? Wk : Wv;
    float s = (which == 0) ? SL2E : 1.0f;
    float4 v = *(const float4*)(src + off);
    v.x *= s; v.y *= s; v.z *= s; v.w *= s;
    *(ushort4*)(Wc + which * 64 * EMB + off) = cvt4(v);
}

// ---------------------------------------------------------------------------
// Projection: X[16384,512] fp32 @ Wc[64,512]^T(bf16) -> bf16.
// 32 rows/block (grid 1536 = 6 blocks/CU). 4 waves: wave w does row-strip
// (w&1), col-half (w>>1). X staged to LDS w/ reg double-buffer; W bf16 frags
// direct from global (L1-hot).
// ---------------------------------------------------------------------------
__global__ __launch_bounds__(256) void proj_kernel(
    const float* __restrict__ q, const float* __restrict__ k, const float* __restrict__ v,
    const __hip_bfloat16* __restrict__ Wc,
    __hip_bfloat16* __restrict__ Qo, __hip_bfloat16* __restrict__ Ko,
    __hip_bfloat16* __restrict__ Vto)
{
    __shared__ __hip_bfloat16 Xs[32][LDX];

    const int which = blockIdx.y;
    const float* __restrict__ x = (which == 0) ? q : (which == 1) ? k : v;
    const __hip_bfloat16* __restrict__ W = Wc + which * 64 * EMB;

    const int tid  = threadIdx.x;
    const int wave = tid >> 6, lane = tid & 63;
    const int l16  = lane & 15, quad = lane >> 4;
    const int rs   = (wave & 1) * 16;        // row strip within block
    const int ch   = wave >> 1;              // col half: t in {2ch, 2ch+1}
    const int r0   = blockIdx.x * 32;
    const float* __restrict__ xb = x + (size_t)r0 * EMB;

    const int sr = tid >> 4;                 // 0..15 staging row base
    const int sc = (tid & 15) << 2;

    const f32x4 z = {0.f, 0.f, 0.f, 0.f};
    f32x4 acc[2] = {z, z};

    float4 xr[2];
    bf16x8 wf[4];

#define LOADX(dst, e0)                                                        \
    _Pragma("unroll")                                                         \
    for (int it = 0; it < 2; ++it)                                            \
        dst[it] = *(const float4*)(xb + (size_t)(it * 16 + sr) * EMB + (e0) + sc);

#define LOADW(dst, e0)                                                        \
    _Pragma("unroll")                                                         \
    for (int st = 0; st < 2; ++st)                                            \
        _Pragma("unroll")                                                     \
        for (int tt = 0; tt < 2; ++tt)                                        \
            dst[st * 2 + tt] = *(const bf16x8*)(W + (size_t)((ch * 2 + tt) * 16 + l16) * EMB \
                                                + (e0) + st * 32 + quad * 8);

    LOADX(xr, 0);
    LOADW(wf, 0);

    #pragma unroll
    for (int c = 0; c < 8; ++c) {
        const int e0 = c * 64;
        if (c) __syncthreads();
        #pragma unroll
        for (int it = 0; it < 2; ++it)
            *(ushort4*)&Xs[it * 16 + sr][sc] = cvt4(xr[it]);
        __syncthreads();

        bf16x8 a0 = *(const bf16x8*)&Xs[rs + l16][quad * 8];
        bf16x8 a1 = *(const bf16x8*)&Xs[rs + l16][32 + quad * 8];

        float4 xr2[2];
        bf16x8 wf2[4];
        if (c < 7) { LOADX(xr2, e0 + 64); LOADW(wf2, e0 + 64); }

        #pragma unroll
        for (int tt = 0; tt < 2; ++tt)
            acc[tt] = __builtin_amdgcn_mfma_f32_16x16x32_bf16(a0, wf[tt], acc[tt], 0, 0, 0);
        #pragma unroll
        for (int tt = 0; tt < 2; ++tt)
            acc[tt] = __builtin_amdgcn_mfma_f32_16x16x32_bf16(a1, wf[2 + tt], acc[tt], 0, 0, 0);

        if (c < 7) {
            #pragma unroll
            for (int it = 0; it < 2; ++it) xr[it] = xr2[it];
            #pragma unroll
            for (int j = 0; j < 4; ++j) wf[j] = wf2[j];
        }
    }
#undef LOADX
#undef LOADW

    #pragma unroll
    for (int tt = 0; tt < 2; ++tt) {
        #pragma unroll
        for (int r = 0; r < 4; ++r) {
            int row = r0 + rs + quad * 4 + r;
            int h   = (ch * 2 + tt) * 16 + l16;
            __hip_bfloat16 val = __float2bfloat16(acc[tt][r]);
            if (which == 0) {
                Qo[(size_t)row * HEAD + h] = val;   // already scaled via Wc
            } else if (which == 1) {
                Ko[(size_t)row * HEAD + h] = val;
            } else {
                int b = row >> 12, s = row & (SEQ - 1);
                Vto[((size_t)b * HEAD + h) * SEQ + s] = val;
            }
        }
    }
}

// ---------------------------------------------------------------------------
// Flash attention — R10: REVERT to the R1 winning structure (128 q-rows/
// block, 4 waves x 2 strips of 16, K/V staged in LDS, 4 blocks/CU; R3's
// 64-q/wave at 2 blocks/CU lost more to latency exposure than it saved in
// LDS slots — occupancy is binding, never trade it below 4 blocks/CU).
// Kept from R3, applied to this structure:
//   * PV loop reorder: vf loaded once per (st,t) OUTSIDE the s loop —
//     8 ds_read_b128/wave-tile instead of R1's 16 (only 4 vf live at once,
//     no register-pressure cost).
//   * Register double-buffered K/V staging: next tile's global loads issue
//     right after the current LDS write; the per-tile vmcnt stall (which
//     ALL 16 resident waves paid synchronously at the barrier in R1) now
//     hides under ~2600 cyc of tile compute.
// R7 swapped QK^T retained: P staged k-contiguous, 8x ds_write_b64.
// LDS 36.9 KB/block; launch_bounds(256,4), grid 1024 = 256 CU x 4 exact.
// Fixed-m softmax (Q pre-scaled by SL2E); l via MFMA against ones.
// Disjoint fp32 partials per split; merge_kernel combines.
// ---------------------------------------------------------------------------
__global__ __launch_bounds__(256, 4) void attn_kernel(
    const __hip_bfloat16* __restrict__ Qb, const __hip_bfloat16* __restrict__ Kb,
    const __hip_bfloat16* __restrict__ Vt, float* __restrict__ Op,
    float* __restrict__ lp)
{
    __shared__ __hip_bfloat16 Ks[64][LDX];
    __shared__ __hip_bfloat16 Vs[64][LDX];    // V^T tile [d][kv]
    __shared__ __hip_bfloat16 Ps[128][LDX];   // P staging (wave-private strips)

    const int tid  = threadIdx.x;
    const int wave = tid >> 6, lane = tid & 63;
    const int l16  = lane & 15, quad = lane >> 4;
    const int b    = blockIdx.y;
    const int q0   = blockIdx.x * 128;
    const int j0b  = blockIdx.z * (SEQ / NSPLIT);
    const int NT   = SEQ / NSPLIT / 64;       // 8 kv-tiles per split

    // Q B-frags direct from global: rows q0 + wave*32 + s*16 + l16
    bf16x8 qf[2][2];
    #pragma unroll
    for (int s = 0; s < 2; ++s) {
        const __hip_bfloat16* qrow =
            Qb + ((size_t)b * SEQ + q0 + wave * 32 + s * 16 + l16) * HEAD + quad * 8;
        qf[s][0] = *(const bf16x8*)(qrow);
        qf[s][1] = *(const bf16x8*)(qrow + 32);
    }

    const f32x4 z = {0.f, 0.f, 0.f, 0.f};
    f32x4 oacc[2][4] = {{z, z, z, z}, {z, z, z, z}};
    f32x4 lacc[2] = {z, z};

    const __hip_bfloat16 one_bf = __float2bfloat16(1.0f);
    bf16x8 ones;
    #pragma unroll
    for (int j = 0; j < 8; ++j) ones[j] = *(const __bf16*)&one_bf;

    // staging indices: thread covers rows sr0 and sr0+32, col sc8
    const int sr0 = tid >> 3;                 // 0..31
    const int sc8 = (tid & 7) * 8;

#define STAGE_LOAD(j0)                                                        \
    _Pragma("unroll")                                                         \
    for (int it = 0; it < 2; ++it) {                                          \
        int r = sr0 + it * 32;                                                \
        kr[it] = *(const uint4*)(Kb + ((size_t)b * SEQ + (j0) + r) * HEAD + sc8); \
        vr[it] = *(const uint4*)(Vt + ((size_t)b * HEAD + r) * SEQ + (j0) + sc8); \
    }

    uint4 kr[2], vr[2];
    STAGE_LOAD(j0b);

    for (int jt = 0; jt < NT; ++jt) {
        __syncthreads();
        #pragma unroll
        for (int it = 0; it < 2; ++it) {
            int r = sr0 + it * 32;
            *(uint4*)&Ks[r][sc8] = kr[it];
            *(uint4*)&Vs[r][sc8] = vr[it];
        }
        __syncthreads();

        if (jt + 1 < NT) { STAGE_LOAD(j0b + (jt + 1) * 64); }

        // S^T = K Q^T  (swapped: lane holds S[k=16t+4*quad+r][q=l16])
        f32x4 sacc[2][4] = {{z, z, z, z}, {z, z, z, z}};
        #pragma unroll
        for (int st = 0; st < 2; ++st) {
            #pragma unroll
            for (int t = 0; t < 4; ++t) {
                bf16x8 kf = *(const bf16x8*)&Ks[t * 16 + l16][st * 32 + quad * 8];
                #pragma unroll
                for (int s = 0; s < 2; ++s)
                    sacc[s][t] = __builtin_amdgcn_mfma_f32_16x16x32_bf16(kf, qf[s][st], sacc[s][t], 0, 0, 0);
            }
        }

        // p = exp2(s); pack 4 k-contiguous bf16 -> one 8B LDS write per (s,t)
        #pragma unroll
        for (int s = 0; s < 2; ++s)
            #pragma unroll
            for (int t = 0; t < 4; ++t) {
                float4 p;
                p.x = __builtin_amdgcn_exp2f(sacc[s][t][0]);
                p.y = __builtin_amdgcn_exp2f(sacc[s][t][1]);
                p.z = __builtin_amdgcn_exp2f(sacc[s][t][2]);
                p.w = __builtin_amdgcn_exp2f(sacc[s][t][3]);
                *(ushort4*)&Ps[wave * 32 + s * 16 + l16][t * 16 + quad * 4] = cvt4(p);
            }

        // O += P V ; l += P * ones  (vf hoisted out of s loop: 8 reads not 16;
        // P strips wave-private: lgkmcnt-only RAW)
        #pragma unroll
        for (int st = 0; st < 2; ++st) {
            bf16x8 vf[4];
            #pragma unroll
            for (int t = 0; t < 4; ++t)
                vf[t] = *(const bf16x8*)&Vs[t * 16 + l16][st * 32 + quad * 8];
            #pragma unroll
            for (int s = 0; s < 2; ++s) {
                bf16x8 pf = *(const bf16x8*)&Ps[wave * 32 + s * 16 + l16][st * 32 + quad * 8];
                lacc[s] = __builtin_amdgcn_mfma_f32_16x16x32_bf16(pf, ones, lacc[s], 0, 0, 0);
                #pragma unroll
                for (int t = 0; t < 4; ++t)
                    oacc[s][t] = __builtin_amdgcn_mfma_f32_16x16x32_bf16(pf, vf[t], oacc[s][t], 0, 0, 0);
            }
        }
    }
#undef STAGE_LOAD

    // epilogue: disjoint fp32 partials
    const size_t pb = (size_t)(blockIdx.z * NB + b) * SEQ;
    #pragma unroll
    for (int s = 0; s < 2; ++s) {
        const size_t row0 = pb + q0 + wave * 32 + s * 16 + quad * 4;
        if (l16 == 0) {
            #pragma unroll
            for (int r = 0; r < 4; ++r)
                lp[row0 + r] = lacc[s][r];
        }
        #pragma unroll
        for (int t = 0; t < 4; ++t)
            #pragma unroll
            for (int r = 0; r < 4; ++r)
                Op[(row0 + r) * HEAD + t * 16 + l16] = oacc[s][t][r];
    }
}

// ---------------------------------------------------------------------------
// Merge: out = (sum_s O_s) / (sum_s l_s)
// ---------------------------------------------------------------------------
__global__ __launch_bounds__(256) void merge_kernel(
    const float* __restrict__ Op, const float* __restrict__ lp,
    float* __restrict__ out)
{
    int idx = blockIdx.x * 256 + threadIdx.x;   // [0, B*S*16)
    int bq  = idx >> 4;
    int c4  = (idx & 15) * 4;
    float4 acc = {0.f, 0.f, 0.f, 0.f};
    float  l   = 0.f;
    #pragma unroll
    for (int s = 0; s < NSPLIT; ++s) {
        float4 o = *(const float4*)(Op + ((size_t)s * NB * SEQ + bq) * HEAD + c4);
        acc.x += o.x; acc.y += o.y; acc.z += o.z; acc.w += o.w;
        l += lp[(size_t)s * NB * SEQ + bq];
    }
    float inv = 1.f / l;
    float4 r = {acc.x * inv, acc.y * inv, acc.z * inv, acc.w * inv};
    *(float4*)(out + (size_t)bq * HEAD + c4) = r;
}

extern "C" void kernel_launch(void* const* d_in, const int* in_sizes, int n_in,
                              void* d_out, int out_size, void* d_ws, size_t ws_size,
                              hipStream_t stream) {
    const float* q  = (const float*)d_in[0];
    const float* k  = (const float*)d_in[1];
    const float* v  = (const float*)d_in[2];
    const float* Wq = (const float*)d_in[3];
    const float* Wk = (const float*)d_in[4];
    const float* Wv = (const float*)d_in[5];
    float* out = (float*)d_out;

    // ws: Qb 2MB | Kb 2MB | Vt 2MB | Wc 192KB | Op 32MB | lp 512KB (~38.7MB)
    __hip_bfloat16* Qb = (__hip_bfloat16*)d_ws;
    __hip_bfloat16* Kb = Qb + (size_t)NB * SEQ * HEAD;
    __hip_bfloat16* Vt = Kb + (size_t)NB * SEQ * HEAD;
    __hip_bfloat16* Wc = Vt + (size_t)NB * SEQ * HEAD;
    float* Op = (float*)(Wc + 3 * 64 * EMB);
    float* lp = Op + (size_t)NSPLIT * NB * SEQ * HEAD;

    cvtw_kernel<<<96, 256, 0, stream>>>(Wq, Wk, Wv, Wc);

    dim3 pgrid(NB * SEQ / 32, 3);
    proj_kernel<<<pgrid, dim3(256), 0, stream>>>(q, k, v, Wc, Qb, Kb, Vt);

    dim3 agrid(SEQ / 128, NB, NSPLIT);
    attn_kernel<<<agrid, dim3(256), 0, stream>>>(Qb, Kb, Vt, Op, lp);

    merge_kernel<<<(NB * SEQ * 16) / 256, dim3(256), 0, stream>>>(Op, lp, out);
}

// Round 5
// 173.514 us; speedup vs baseline: 1.1221x; 1.1221x over previous
//
#include <hip/hip_runtime.h>
#include <hip/hip_bf16.h>

#define EMB    512
#define HEAD   64
#define SEQ    4096
#define NB     4
#define NSPLIT 8
#define LDX    72   // padded LDS row stride (144 B, 16B-aligned)

#define SL2E   0.18033688011112042f   // (1/sqrt(64)) * log2(e), folded into Wq

typedef __bf16 bf16x8 __attribute__((ext_vector_type(8)));
typedef float  f32x4  __attribute__((ext_vector_type(4)));

__device__ inline ushort4 cvt4(float4 v) {
    __hip_bfloat16 a = __float2bfloat16(v.x), b = __float2bfloat16(v.y);
    __hip_bfloat16 c = __float2bfloat16(v.z), d = __float2bfloat16(v.w);
    ushort4 r;
    r.x = *(unsigned short*)&a; r.y = *(unsigned short*)&b;
    r.z = *(unsigned short*)&c; r.w = *(unsigned short*)&d;
    return r;
}

// ---------------------------------------------------------------------------
// One-shot W convert: [3][64][512] fp32 -> bf16; Wq pre-scaled by SL2E.
// ---------------------------------------------------------------------------
__global__ __launch_bounds__(256) void cvtw_kernel(
    const float* __restrict__ Wq, const float* __restrict__ Wk,
    const float* __restrict__ Wv, __hip_bfloat16* __restrict__ Wc)
{
    int idx   = blockIdx.x * 256 + threadIdx.x;
    int which = idx >> 13;
    int off   = (idx & 8191) * 4;
    const float* src = (which == 0) ? Wq : (which == 1) ? Wk : Wv;
    float s = (which == 0) ? SL2E : 1.0f;
    float4 v = *(const float4*)(src + off);
    v.x *= s; v.y *= s; v.z *= s; v.w *= s;
    *(ushort4*)(Wc + which * 64 * EMB + off) = cvt4(v);
}

// ---------------------------------------------------------------------------
// Projection: X[16384,512] fp32 @ Wc[64,512]^T(bf16) -> bf16.
// 32 rows/block (grid 1536 = 6 blocks/CU). 4 waves: wave w does row-strip
// (w&1), col-half (w>>1). X staged to LDS w/ reg double-buffer; W bf16 frags
// direct from global (L1-hot).
// ---------------------------------------------------------------------------
__global__ __launch_bounds__(256) void proj_kernel(
    const float* __restrict__ q, const float* __restrict__ k, const float* __restrict__ v,
    const __hip_bfloat16* __restrict__ Wc,
    __hip_bfloat16* __restrict__ Qo, __hip_bfloat16* __restrict__ Ko,
    __hip_bfloat16* __restrict__ Vto)
{
    __shared__ __hip_bfloat16 Xs[32][LDX];

    const int which = blockIdx.y;
    const float* __restrict__ x = (which == 0) ? q : (which == 1) ? k : v;
    const __hip_bfloat16* __restrict__ W = Wc + which * 64 * EMB;

    const int tid  = threadIdx.x;
    const int wave = tid >> 6, lane = tid & 63;
    const int l16  = lane & 15, quad = lane >> 4;
    const int rs   = (wave & 1) * 16;        // row strip within block
    const int ch   = wave >> 1;              // col half: t in {2ch, 2ch+1}
    const int r0   = blockIdx.x * 32;
    const float* __restrict__ xb = x + (size_t)r0 * EMB;

    const int sr = tid >> 4;                 // 0..15 staging row base
    const int sc = (tid & 15) << 2;

    const f32x4 z = {0.f, 0.f, 0.f, 0.f};
    f32x4 acc[2] = {z, z};

    float4 xr[2];
    bf16x8 wf[4];

#define LOADX(dst, e0)                                                        \
    _Pragma("unroll")                                                         \
    for (int it = 0; it < 2; ++it)                                            \
        dst[it] = *(const float4*)(xb + (size_t)(it * 16 + sr) * EMB + (e0) + sc);

#define LOADW(dst, e0)                                                        \
    _Pragma("unroll")                                                         \
    for (int st = 0; st < 2; ++st)                                            \
        _Pragma("unroll")                                                     \
        for (int tt = 0; tt < 2; ++tt)                                        \
            dst[st * 2 + tt] = *(const bf16x8*)(W + (size_t)((ch * 2 + tt) * 16 + l16) * EMB \
                                                + (e0) + st * 32 + quad * 8);

    LOADX(xr, 0);
    LOADW(wf, 0);

    #pragma unroll
    for (int c = 0; c < 8; ++c) {
        const int e0 = c * 64;
        if (c) __syncthreads();
        #pragma unroll
        for (int it = 0; it < 2; ++it)
            *(ushort4*)&Xs[it * 16 + sr][sc] = cvt4(xr[it]);
        __syncthreads();

        bf16x8 a0 = *(const bf16x8*)&Xs[rs + l16][quad * 8];
        bf16x8 a1 = *(const bf16x8*)&Xs[rs + l16][32 + quad * 8];

        float4 xr2[2];
        bf16x8 wf2[4];
        if (c < 7) { LOADX(xr2, e0 + 64); LOADW(wf2, e0 + 64); }

        #pragma unroll
        for (int tt = 0; tt < 2; ++tt)
            acc[tt] = __builtin_amdgcn_mfma_f32_16x16x32_bf16(a0, wf[tt], acc[tt], 0, 0, 0);
        #pragma unroll
        for (int tt = 0; tt < 2; ++tt)
            acc[tt] = __builtin_amdgcn_mfma_f32_16x16x32_bf16(a1, wf[2 + tt], acc[tt], 0, 0, 0);

        if (c < 7) {
            #pragma unroll
            for (int it = 0; it < 2; ++it) xr[it] = xr2[it];
            #pragma unroll
            for (int j = 0; j < 4; ++j) wf[j] = wf2[j];
        }
    }
#undef LOADX
#undef LOADW

    #pragma unroll
    for (int tt = 0; tt < 2; ++tt) {
        #pragma unroll
        for (int r = 0; r < 4; ++r) {
            int row = r0 + rs + quad * 4 + r;
            int h   = (ch * 2 + tt) * 16 + l16;
            __hip_bfloat16 val = __float2bfloat16(acc[tt][r]);
            if (which == 0) {
                Qo[(size_t)row * HEAD + h] = val;   // already scaled via Wc
            } else if (which == 1) {
                Ko[(size_t)row * HEAD + h] = val;
            } else {
                int b = row >> 12, s = row & (SEQ - 1);
                Vto[((size_t)b * HEAD + h) * SEQ + s] = val;
            }
        }
    }
}

// ---------------------------------------------------------------------------
// Flash attention — R11: EXACT R1 structure (128 q-rows/block, 4 waves x 2
// strips of 16, K/V staged in LDS via direct global->LDS statements,
// 4 blocks/CU, launch_bounds(256,4)) plus ONE change: PV loop reordered so
// vf[4] is loaded once per st OUTSIDE the s loop (8 ds_read_b128/wave-tile
// instead of 16; ~12 transient VGPRs, sacc dead by then — peak unchanged).
// R4 lesson (scratch spill): NO long-lived register prefetch at this
// occupancy — kr/vr across the compute section spilled to scratch
// (WRITE_SIZE 33->145 MB). R3 lesson: never drop below 4 blocks/CU.
// R7 swapped QK^T retained: P staged k-contiguous, 8x ds_write_b64.
// Fixed-m softmax (Q pre-scaled by SL2E); l via MFMA against ones.
// Disjoint fp32 partials per split; merge_kernel combines.
// ---------------------------------------------------------------------------
__global__ __launch_bounds__(256, 4) void attn_kernel(
    const __hip_bfloat16* __restrict__ Qb, const __hip_bfloat16* __restrict__ Kb,
    const __hip_bfloat16* __restrict__ Vt, float* __restrict__ Op,
    float* __restrict__ lp)
{
    __shared__ __hip_bfloat16 Ks[64][LDX];
    __shared__ __hip_bfloat16 Vs[64][LDX];    // V^T tile [d][kv]
    __shared__ __hip_bfloat16 Ps[128][LDX];   // P staging (wave-private strips)

    const int tid  = threadIdx.x;
    const int wave = tid >> 6, lane = tid & 63;
    const int l16  = lane & 15, quad = lane >> 4;
    const int b    = blockIdx.y;
    const int q0   = blockIdx.x * 128;
    const int j0b  = blockIdx.z * (SEQ / NSPLIT);

    // Q B-frags direct from global: rows q0 + wave*32 + s*16 + l16
    bf16x8 qf[2][2];
    #pragma unroll
    for (int s = 0; s < 2; ++s) {
        const __hip_bfloat16* qrow =
            Qb + ((size_t)b * SEQ + q0 + wave * 32 + s * 16 + l16) * HEAD + quad * 8;
        qf[s][0] = *(const bf16x8*)(qrow);
        qf[s][1] = *(const bf16x8*)(qrow + 32);
    }

    const f32x4 z = {0.f, 0.f, 0.f, 0.f};
    f32x4 oacc[2][4] = {{z, z, z, z}, {z, z, z, z}};
    f32x4 lacc[2] = {z, z};

    const __hip_bfloat16 one_bf = __float2bfloat16(1.0f);
    bf16x8 ones;
    #pragma unroll
    for (int j = 0; j < 8; ++j) ones[j] = *(const __bf16*)&one_bf;

    for (int jt = 0; jt < SEQ / NSPLIT; jt += 64) {
        const int j0 = j0b + jt;
        __syncthreads();
        for (int i = tid; i < 512; i += 256) {
            int r = i >> 3, c8 = (i & 7) * 8;
            *(uint4*)&Ks[r][c8] =
                *(const uint4*)(Kb + ((size_t)b * SEQ + j0 + r) * HEAD + c8);
            *(uint4*)&Vs[r][c8] =
                *(const uint4*)(Vt + ((size_t)b * HEAD + r) * SEQ + j0 + c8);
        }
        __syncthreads();

        // S^T = K Q^T  (swapped: lane holds S[k=16t+4*quad+r][q=l16])
        f32x4 sacc[2][4] = {{z, z, z, z}, {z, z, z, z}};
        #pragma unroll
        for (int st = 0; st < 2; ++st) {
            #pragma unroll
            for (int t = 0; t < 4; ++t) {
                bf16x8 kf = *(const bf16x8*)&Ks[t * 16 + l16][st * 32 + quad * 8];
                #pragma unroll
                for (int s = 0; s < 2; ++s)
                    sacc[s][t] = __builtin_amdgcn_mfma_f32_16x16x32_bf16(kf, qf[s][st], sacc[s][t], 0, 0, 0);
            }
        }

        // p = exp2(s); pack 4 k-contiguous bf16 -> one 8B LDS write per (s,t)
        #pragma unroll
        for (int s = 0; s < 2; ++s)
            #pragma unroll
            for (int t = 0; t < 4; ++t) {
                float4 p;
                p.x = __builtin_amdgcn_exp2f(sacc[s][t][0]);
                p.y = __builtin_amdgcn_exp2f(sacc[s][t][1]);
                p.z = __builtin_amdgcn_exp2f(sacc[s][t][2]);
                p.w = __builtin_amdgcn_exp2f(sacc[s][t][3]);
                *(ushort4*)&Ps[wave * 32 + s * 16 + l16][t * 16 + quad * 4] = cvt4(p);
            }

        // O += P V ; l += P * ones  (vf hoisted out of s loop: 8 reads not 16;
        // P strips wave-private: lgkmcnt-only RAW)
        #pragma unroll
        for (int st = 0; st < 2; ++st) {
            bf16x8 vf[4];
            #pragma unroll
            for (int t = 0; t < 4; ++t)
                vf[t] = *(const bf16x8*)&Vs[t * 16 + l16][st * 32 + quad * 8];
            #pragma unroll
            for (int s = 0; s < 2; ++s) {
                bf16x8 pf = *(const bf16x8*)&Ps[wave * 32 + s * 16 + l16][st * 32 + quad * 8];
                lacc[s] = __builtin_amdgcn_mfma_f32_16x16x32_bf16(pf, ones, lacc[s], 0, 0, 0);
                #pragma unroll
                for (int t = 0; t < 4; ++t)
                    oacc[s][t] = __builtin_amdgcn_mfma_f32_16x16x32_bf16(pf, vf[t], oacc[s][t], 0, 0, 0);
            }
        }
    }

    // epilogue: disjoint fp32 partials
    const size_t pb = (size_t)(blockIdx.z * NB + b) * SEQ;
    #pragma unroll
    for (int s = 0; s < 2; ++s) {
        const size_t row0 = pb + q0 + wave * 32 + s * 16 + quad * 4;
        if (l16 == 0) {
            #pragma unroll
            for (int r = 0; r < 4; ++r)
                lp[row0 + r] = lacc[s][r];
        }
        #pragma unroll
        for (int t = 0; t < 4; ++t)
            #pragma unroll
            for (int r = 0; r < 4; ++r)
                Op[(row0 + r) * HEAD + t * 16 + l16] = oacc[s][t][r];
    }
}

// ---------------------------------------------------------------------------
// Merge: out = (sum_s O_s) / (sum_s l_s)
// ---------------------------------------------------------------------------
__global__ __launch_bounds__(256) void merge_kernel(
    const float* __restrict__ Op, const float* __restrict__ lp,
    float* __restrict__ out)
{
    int idx = blockIdx.x * 256 + threadIdx.x;   // [0, B*S*16)
    int bq  = idx >> 4;
    int c4  = (idx & 15) * 4;
    float4 acc = {0.f, 0.f, 0.f, 0.f};
    float  l   = 0.f;
    #pragma unroll
    for (int s = 0; s < NSPLIT; ++s) {
        float4 o = *(const float4*)(Op + ((size_t)s * NB * SEQ + bq) * HEAD + c4);
        acc.x += o.x; acc.y += o.y; acc.z += o.z; acc.w += o.w;
        l += lp[(size_t)s * NB * SEQ + bq];
    }
    float inv = 1.f / l;
    float4 r = {acc.x * inv, acc.y * inv, acc.z * inv, acc.w * inv};
    *(float4*)(out + (size_t)bq * HEAD + c4) = r;
}

extern "C" void kernel_launch(void* const* d_in, const int* in_sizes, int n_in,
                              void* d_out, int out_size, void* d_ws, size_t ws_size,
                              hipStream_t stream) {
    const float* q  = (const float*)d_in[0];
    const float* k  = (const float*)d_in[1];
    const float* v  = (const float*)d_in[2];
    const float* Wq = (const float*)d_in[3];
    const float* Wk = (const float*)d_in[4];
    const float* Wv = (const float*)d_in[5];
    float* out = (float*)d_out;

    // ws: Qb 2MB | Kb 2MB | Vt 2MB | Wc 192KB | Op 32MB | lp 512KB (~38.7MB)
    __hip_bfloat16* Qb = (__hip_bfloat16*)d_ws;
    __hip_bfloat16* Kb = Qb + (size_t)NB * SEQ * HEAD;
    __hip_bfloat16* Vt = Kb + (size_t)NB * SEQ * HEAD;
    __hip_bfloat16* Wc = Vt + (size_t)NB * SEQ * HEAD;
    float* Op = (float*)(Wc + 3 * 64 * EMB);
    float* lp = Op + (size_t)NSPLIT * NB * SEQ * HEAD;

    cvtw_kernel<<<96, 256, 0, stream>>>(Wq, Wk, Wv, Wc);

    dim3 pgrid(NB * SEQ / 32, 3);
    proj_kernel<<<pgrid, dim3(256), 0, stream>>>(q, k, v, Wc, Qb, Kb, Vt);

    dim3 agrid(SEQ / 128, NB, NSPLIT);
    attn_kernel<<<agrid, dim3(256), 0, stream>>>(Qb, Kb, Vt, Op, lp);

    merge_kernel<<<(NB * SEQ * 16) / 256, dim3(256), 0, stream>>>(Op, lp, out);
}

// Round 8
// 171.631 us; speedup vs baseline: 1.1344x; 1.0110x over previous
//
#include <hip/hip_runtime.h>
#include <hip/hip_bf16.h>

#define EMB    512
#define HEAD   64
#define SEQ    4096
#define NB     4
#define NSPLIT 8
#define LDX    72   // padded LDS row stride for proj (144 B, 16B-aligned)

#define SL2E   0.18033688011112042f   // (1/sqrt(64)) * log2(e), folded into Wq

typedef __bf16 bf16x8 __attribute__((ext_vector_type(8)));
typedef float  f32x4  __attribute__((ext_vector_type(4)));

__device__ inline ushort4 cvt4(float4 v) {
    __hip_bfloat16 a = __float2bfloat16(v.x), b = __float2bfloat16(v.y);
    __hip_bfloat16 c = __float2bfloat16(v.z), d = __float2bfloat16(v.w);
    ushort4 r;
    r.x = *(unsigned short*)&a; r.y = *(unsigned short*)&b;
    r.z = *(unsigned short*)&c; r.w = *(unsigned short*)&d;
    return r;
}

// ---------------------------------------------------------------------------
// One-shot W convert: [3][64][512] fp32 -> bf16; Wq pre-scaled by SL2E.
// ---------------------------------------------------------------------------
__global__ __launch_bounds__(256) void cvtw_kernel(
    const float* __restrict__ Wq, const float* __restrict__ Wk,
    const float* __restrict__ Wv, __hip_bfloat16* __restrict__ Wc)
{
    int idx   = blockIdx.x * 256 + threadIdx.x;
    int which = idx >> 13;
    int off   = (idx & 8191) * 4;
    const float* src = (which == 0) ? Wq : (which == 1) ? Wk : Wv;
    float s = (which == 0) ? SL2E : 1.0f;
    float4 v = *(const float4*)(src + off);
    v.x *= s; v.y *= s; v.z *= s; v.w *= s;
    *(ushort4*)(Wc + which * 64 * EMB + off) = cvt4(v);
}

// ---------------------------------------------------------------------------
// Projection: X[16384,512] fp32 @ Wc[64,512]^T(bf16) -> bf16.  (unchanged)
// ---------------------------------------------------------------------------
__global__ __launch_bounds__(256) void proj_kernel(
    const float* __restrict__ q, const float* __restrict__ k, const float* __restrict__ v,
    const __hip_bfloat16* __restrict__ Wc,
    __hip_bfloat16* __restrict__ Qo, __hip_bfloat16* __restrict__ Ko,
    __hip_bfloat16* __restrict__ Vto)
{
    __shared__ __hip_bfloat16 Xs[32][LDX];

    const int which = blockIdx.y;
    const float* __restrict__ x = (which == 0) ? q : (which == 1) ? k : v;
    const __hip_bfloat16* __restrict__ W = Wc + which * 64 * EMB;

    const int tid  = threadIdx.x;
    const int wave = tid >> 6, lane = tid & 63;
    const int l16  = lane & 15, quad = lane >> 4;
    const int rs   = (wave & 1) * 16;        // row strip within block
    const int ch   = wave >> 1;              // col half: t in {2ch, 2ch+1}
    const int r0   = blockIdx.x * 32;
    const float* __restrict__ xb = x + (size_t)r0 * EMB;

    const int sr = tid >> 4;                 // 0..15 staging row base
    const int sc = (tid & 15) << 2;

    const f32x4 z = {0.f, 0.f, 0.f, 0.f};
    f32x4 acc[2] = {z, z};

    float4 xr[2];
    bf16x8 wf[4];

#define LOADX(dst, e0)                                                        \
    _Pragma("unroll")                                                         \
    for (int it = 0; it < 2; ++it)                                            \
        dst[it] = *(const float4*)(xb + (size_t)(it * 16 + sr) * EMB + (e0) + sc);

#define LOADW(dst, e0)                                                        \
    _Pragma("unroll")                                                         \
    for (int st = 0; st < 2; ++st)                                            \
        _Pragma("unroll")                                                     \
        for (int tt = 0; tt < 2; ++tt)                                        \
            dst[st * 2 + tt] = *(const bf16x8*)(W + (size_t)((ch * 2 + tt) * 16 + l16) * EMB \
                                                + (e0) + st * 32 + quad * 8);

    LOADX(xr, 0);
    LOADW(wf, 0);

    #pragma unroll
    for (int c = 0; c < 8; ++c) {
        const int e0 = c * 64;
        if (c) __syncthreads();
        #pragma unroll
        for (int it = 0; it < 2; ++it)
            *(ushort4*)&Xs[it * 16 + sr][sc] = cvt4(xr[it]);
        __syncthreads();

        bf16x8 a0 = *(const bf16x8*)&Xs[rs + l16][quad * 8];
        bf16x8 a1 = *(const bf16x8*)&Xs[rs + l16][32 + quad * 8];

        float4 xr2[2];
        bf16x8 wf2[4];
        if (c < 7) { LOADX(xr2, e0 + 64); LOADW(wf2, e0 + 64); }

        #pragma unroll
        for (int tt = 0; tt < 2; ++tt)
            acc[tt] = __builtin_amdgcn_mfma_f32_16x16x32_bf16(a0, wf[tt], acc[tt], 0, 0, 0);
        #pragma unroll
        for (int tt = 0; tt < 2; ++tt)
            acc[tt] = __builtin_amdgcn_mfma_f32_16x16x32_bf16(a1, wf[2 + tt], acc[tt], 0, 0, 0);

        if (c < 7) {
            #pragma unroll
            for (int it = 0; it < 2; ++it) xr[it] = xr2[it];
            #pragma unroll
            for (int j = 0; j < 4; ++j) wf[j] = wf2[j];
        }
    }
#undef LOADX
#undef LOADW

    #pragma unroll
    for (int tt = 0; tt < 2; ++tt) {
        #pragma unroll
        for (int r = 0; r < 4; ++r) {
            int row = r0 + rs + quad * 4 + r;
            int h   = (ch * 2 + tt) * 16 + l16;
            __hip_bfloat16 val = __float2bfloat16(acc[tt][r]);
            if (which == 0) {
                Qo[(size_t)row * HEAD + h] = val;   // already scaled via Wc
            } else if (which == 1) {
                Ko[(size_t)row * HEAD + h] = val;
            } else {
                int b = row >> 12, s = row & (SEQ - 1);
                Vto[((size_t)b * HEAD + h) * SEQ + s] = val;
            }
        }
    }
}

// ---------------------------------------------------------------------------
// Flash attention — R14 = R12 pipeline + FULL memory-fence discipline.
// R13 diagnosis was incomplete: sched_barrier(0) is IntrNoMem — IR passes
// may move LDS ops across it; and raw s_barrier (unlike __syncthreads) is
// NOT an IR memory fence either. True races:
//  (1) kf/vf ds_reads hoisted above the first s_barrier -> read other
//      waves' rows before their staging landed;
//  (2) waves passing the end s_barrier with DS reads issued-but-pending
//      while the next glds re-stages the same buffer.
// Fix (m201 discipline): every raw s_barrier flanked by asm-"memory"
// fences; s_waitcnt lgkmcnt(0) before the end barrier; asm-"memory" +
// sched_barrier(0) around the Ps round-trip (cross-lane deps invisible to
// LLVM's per-thread alias model). Pipeline unchanged: glds staging (zero
// VGPRs), double-buffered K/V, counted vmcnt(4) — never vmcnt(0) in-loop.
// Unpadded [64][64] tiles, XOR-16B-chunk swizzle both sides (T21).
// Strip-serial compute, 16-row wave-private Ps; LDS 40KB -> 4 blocks/CU.
// Fixed-m softmax (Q pre-scaled by SL2E); l via MFMA against ones.
// ---------------------------------------------------------------------------
__global__ __launch_bounds__(256, 4) void attn_kernel(
    const __hip_bfloat16* __restrict__ Qb, const __hip_bfloat16* __restrict__ Kb,
    const __hip_bfloat16* __restrict__ Vt, float* __restrict__ Op,
    float* __restrict__ lp)
{
    __shared__ __hip_bfloat16 KsF[2][64][64];
    __shared__ __hip_bfloat16 VsF[2][64][64];   // V^T tile [d][kv]
    __shared__ __hip_bfloat16 PsF[64][64];      // 4 waves x 16 private rows

    const int tid  = threadIdx.x;
    const int wave = tid >> 6, lane = tid & 63;
    const int l16  = lane & 15, quad = lane >> 4;
    const int b    = blockIdx.y;
    const int q0   = blockIdx.x * 128;
    const int j0b  = blockIdx.z * (SEQ / NSPLIT);

    // Q B-frags direct from global: rows q0 + wave*32 + s*16 + l16
    bf16x8 qf[2][2];
    #pragma unroll
    for (int s = 0; s < 2; ++s) {
        const __hip_bfloat16* qrow =
            Qb + ((size_t)b * SEQ + q0 + wave * 32 + s * 16 + l16) * HEAD + quad * 8;
        qf[s][0] = *(const bf16x8*)(qrow);
        qf[s][1] = *(const bf16x8*)(qrow + 32);
    }

    // glds staging: wave w stages rows [w*16, w*16+16) of K and V tiles.
    // lane λ covers row (λ>>3) (+8 for it=1), 16B chunk (λ&7)^((λ>>3)&7)
    // (inverse swizzle on the SOURCE; LDS dest is linear base + λ*16).
    const int rl  = lane >> 3;                // 0..7
    const int ch8 = (lane & 7) ^ rl;          // swizzled 16B-chunk index
    const __hip_bfloat16* __restrict__ Ksrc0 =
        Kb + ((size_t)b * SEQ + wave * 16 + rl) * HEAD + ch8 * 8;
    const __hip_bfloat16* __restrict__ Vsrc0 =
        Vt + ((size_t)b * HEAD + wave * 16 + rl) * SEQ + ch8 * 8;

#define STAGE(bufi, j0)                                                       \
    do {                                                                      \
        _Pragma("unroll")                                                     \
        for (int it = 0; it < 2; ++it) {                                      \
            __builtin_amdgcn_global_load_lds(                                 \
                (const __attribute__((address_space(1))) unsigned int*)       \
                    (const void*)(Ksrc0 + ((size_t)(j0) + it * 8) * HEAD),    \
                (__attribute__((address_space(3))) unsigned int*)             \
                    (void*)&KsF[bufi][wave * 16 + it * 8][0], 16, 0, 0);      \
            __builtin_amdgcn_global_load_lds(                                 \
                (const __attribute__((address_space(1))) unsigned int*)       \
                    (const void*)(Vsrc0 + (j0) + (size_t)it * 8 * SEQ),       \
                (__attribute__((address_space(3))) unsigned int*)             \
                    (void*)&VsF[bufi][wave * 16 + it * 8][0], 16, 0, 0);      \
        }                                                                     \
    } while (0)

    const f32x4 z = {0.f, 0.f, 0.f, 0.f};
    f32x4 oacc[2][4] = {{z, z, z, z}, {z, z, z, z}};
    f32x4 lacc[2] = {z, z};

    const __hip_bfloat16 one_bf = __float2bfloat16(1.0f);
    bf16x8 ones;
    #pragma unroll
    for (int j = 0; j < 8; ++j) ones[j] = *(const __bf16*)&one_bf;

    STAGE(0, j0b);                            // prologue: tile 0 -> buf 0

    const int xs = l16 & 7;                   // read-side XOR (row&7)

    #pragma unroll
    for (int jt = 0; jt < SEQ / NSPLIT / 64; ++jt) {
        const int cur = jt & 1;
        if (jt < SEQ / NSPLIT / 64 - 1) {
            STAGE(cur ^ 1, j0b + (jt + 1) * 64);
            asm volatile("s_waitcnt vmcnt(4)" ::: "memory");
        } else {
            asm volatile("s_waitcnt vmcnt(0)" ::: "memory");
        }
        __builtin_amdgcn_sched_barrier(0);
        __builtin_amdgcn_s_barrier();
        // IR+machine fence: no LDS read of the fresh buffer may hoist above
        // the barrier (other waves' rows only guaranteed landed after it).
        asm volatile("" ::: "memory");

        #pragma unroll
        for (int s = 0; s < 2; ++s) {
            // S^T = K Q^T (swapped: lane holds S[k=16t+4*quad+r][q=l16])
            f32x4 sacc[4] = {z, z, z, z};
            #pragma unroll
            for (int st = 0; st < 2; ++st)
                #pragma unroll
                for (int t = 0; t < 4; ++t) {
                    bf16x8 kf = *(const bf16x8*)
                        &KsF[cur][t * 16 + l16][((st * 4 + quad) ^ xs) * 8];
                    sacc[t] = __builtin_amdgcn_mfma_f32_16x16x32_bf16(kf, qf[s][st], sacc[t], 0, 0, 0);
                }

            // Fence: prev strip's pf ds_reads stay BEFORE these ds_writes
            // (cross-lane WAR invisible to per-thread alias analysis).
            asm volatile("" ::: "memory");
            __builtin_amdgcn_sched_barrier(0);

            // p = exp2(s); pack 4 k-contiguous bf16 -> one swizzled 8B write
            #pragma unroll
            for (int t = 0; t < 4; ++t) {
                float4 p;
                p.x = __builtin_amdgcn_exp2f(sacc[t][0]);
                p.y = __builtin_amdgcn_exp2f(sacc[t][1]);
                p.z = __builtin_amdgcn_exp2f(sacc[t][2]);
                p.w = __builtin_amdgcn_exp2f(sacc[t][3]);
                *(ushort4*)&PsF[wave * 16 + l16]
                    [(((t * 2 + (quad >> 1)) ^ xs) * 8) + (quad & 1) * 4] = cvt4(p);
            }

            // Fence: the ds_writes stay BEFORE this strip's pf ds_reads
            // (cross-lane RAW; per-wave DS pipe executes in program order).
            asm volatile("" ::: "memory");
            __builtin_amdgcn_sched_barrier(0);

            // O += P V ; l += P * ones
            #pragma unroll
            for (int st = 0; st < 2; ++st) {
                bf16x8 pf = *(const bf16x8*)
                    &PsF[wave * 16 + l16][((st * 4 + quad) ^ xs) * 8];
                lacc[s] = __builtin_amdgcn_mfma_f32_16x16x32_bf16(pf, ones, lacc[s], 0, 0, 0);
                #pragma unroll
                for (int t = 0; t < 4; ++t) {
                    bf16x8 vf = *(const bf16x8*)
                        &VsF[cur][t * 16 + l16][((st * 4 + quad) ^ xs) * 8];
                    oacc[s][t] = __builtin_amdgcn_mfma_f32_16x16x32_bf16(pf, vf, oacc[s][t], 0, 0, 0);
                }
            }
        }
        // Drain this wave's DS reads BEFORE the end barrier so the next
        // iteration's glds cannot overwrite a buffer with reads pending
        // (compiler's own lgkm waits may have sunk past the barrier).
        asm volatile("s_waitcnt lgkmcnt(0)" ::: "memory");
        __builtin_amdgcn_sched_barrier(0);
        __builtin_amdgcn_s_barrier();
        asm volatile("" ::: "memory");   // STAGE may not hoist above barrier
    }
#undef STAGE

    // epilogue: disjoint fp32 partials
    const size_t pb = (size_t)(blockIdx.z * NB + b) * SEQ;
    #pragma unroll
    for (int s = 0; s < 2; ++s) {
        const size_t row0 = pb + q0 + wave * 32 + s * 16 + quad * 4;
        if (l16 == 0) {
            #pragma unroll
            for (int r = 0; r < 4; ++r)
                lp[row0 + r] = lacc[s][r];
        }
        #pragma unroll
        for (int t = 0; t < 4; ++t)
            #pragma unroll
            for (int r = 0; r < 4; ++r)
                Op[(row0 + r) * HEAD + t * 16 + l16] = oacc[s][t][r];
    }
}

// ---------------------------------------------------------------------------
// Merge: out = (sum_s O_s) / (sum_s l_s)
// ---------------------------------------------------------------------------
__global__ __launch_bounds__(256) void merge_kernel(
    const float* __restrict__ Op, const float* __restrict__ lp,
    float* __restrict__ out)
{
    int idx = blockIdx.x * 256 + threadIdx.x;   // [0, B*S*16)
    int bq  = idx >> 4;
    int c4  = (idx & 15) * 4;
    float4 acc = {0.f, 0.f, 0.f, 0.f};
    float  l   = 0.f;
    #pragma unroll
    for (int s = 0; s < NSPLIT; ++s) {
        float4 o = *(const float4*)(Op + ((size_t)s * NB * SEQ + bq) * HEAD + c4);
        acc.x += o.x; acc.y += o.y; acc.z += o.z; acc.w += o.w;
        l += lp[(size_t)s * NB * SEQ + bq];
    }
    float inv = 1.f / l;
    float4 r = {acc.x * inv, acc.y * inv, acc.z * inv, acc.w * inv};
    *(float4*)(out + (size_t)bq * HEAD + c4) = r;
}

extern "C" void kernel_launch(void* const* d_in, const int* in_sizes, int n_in,
                              void* d_out, int out_size, void* d_ws, size_t ws_size,
                              hipStream_t stream) {
    const float* q  = (const float*)d_in[0];
    const float* k  = (const float*)d_in[1];
    const float* v  = (const float*)d_in[2];
    const float* Wq = (const float*)d_in[3];
    const float* Wk = (const float*)d_in[4];
    const float* Wv = (const float*)d_in[5];
    float* out = (float*)d_out;

    // ws: Qb 2MB | Kb 2MB | Vt 2MB | Wc 192KB | Op 32MB | lp 512KB (~38.7MB)
    __hip_bfloat16* Qb = (__hip_bfloat16*)d_ws;
    __hip_bfloat16* Kb = Qb + (size_t)NB * SEQ * HEAD;
    __hip_bfloat16* Vt = Kb + (size_t)NB * SEQ * HEAD;
    __hip_bfloat16* Wc = Vt + (size_t)NB * SEQ * HEAD;
    float* Op = (float*)(Wc + 3 * 64 * EMB);
    float* lp = Op + (size_t)NSPLIT * NB * SEQ * HEAD;

    cvtw_kernel<<<96, 256, 0, stream>>>(Wq, Wk, Wv, Wc);

    dim3 pgrid(NB * SEQ / 32, 3);
    proj_kernel<<<pgrid, dim3(256), 0, stream>>>(q, k, v, Wc, Qb, Kb, Vt);

    dim3 agrid(SEQ / 128, NB, NSPLIT);
    attn_kernel<<<agrid, dim3(256), 0, stream>>>(Qb, Kb, Vt, Op, lp);

    merge_kernel<<<(NB * SEQ * 16) / 256, dim3(256), 0, stream>>>(Op, lp, out);
}

// Round 9
// 169.557 us; speedup vs baseline: 1.1483x; 1.0122x over previous
//
#include <hip/hip_runtime.h>
#include <hip/hip_bf16.h>

#define EMB    512
#define HEAD   64
#define SEQ    4096
#define NB     4
#define NSPLIT 8
#define LDX    72   // padded LDS row stride for proj (144 B, 16B-aligned)

#define SL2E   0.18033688011112042f   // (1/sqrt(64)) * log2(e), folded into Wq

typedef __bf16 bf16x8 __attribute__((ext_vector_type(8)));
typedef float  f32x4  __attribute__((ext_vector_type(4)));

__device__ inline ushort4 cvt4(float4 v) {
    __hip_bfloat16 a = __float2bfloat16(v.x), b = __float2bfloat16(v.y);
    __hip_bfloat16 c = __float2bfloat16(v.z), d = __float2bfloat16(v.w);
    ushort4 r;
    r.x = *(unsigned short*)&a; r.y = *(unsigned short*)&b;
    r.z = *(unsigned short*)&c; r.w = *(unsigned short*)&d;
    return r;
}

// ---------------------------------------------------------------------------
// One-shot W convert: [3][64][512] fp32 -> bf16; Wq pre-scaled by SL2E.
// ---------------------------------------------------------------------------
__global__ __launch_bounds__(256) void cvtw_kernel(
    const float* __restrict__ Wq, const float* __restrict__ Wk,
    const float* __restrict__ Wv, __hip_bfloat16* __restrict__ Wc)
{
    int idx   = blockIdx.x * 256 + threadIdx.x;
    int which = idx >> 13;
    int off   = (idx & 8191) * 4;
    const float* src = (which == 0) ? Wq : (which == 1) ? Wk : Wv;
    float s = (which == 0) ? SL2E : 1.0f;
    float4 v = *(const float4*)(src + off);
    v.x *= s; v.y *= s; v.z *= s; v.w *= s;
    *(ushort4*)(Wc + which * 64 * EMB + off) = cvt4(v);
}

// ---------------------------------------------------------------------------
// Projection: X[16384,512] fp32 @ Wc[64,512]^T(bf16) -> bf16.  (unchanged)
// ---------------------------------------------------------------------------
__global__ __launch_bounds__(256) void proj_kernel(
    const float* __restrict__ q, const float* __restrict__ k, const float* __restrict__ v,
    const __hip_bfloat16* __restrict__ Wc,
    __hip_bfloat16* __restrict__ Qo, __hip_bfloat16* __restrict__ Ko,
    __hip_bfloat16* __restrict__ Vto)
{
    __shared__ __hip_bfloat16 Xs[32][LDX];

    const int which = blockIdx.y;
    const float* __restrict__ x = (which == 0) ? q : (which == 1) ? k : v;
    const __hip_bfloat16* __restrict__ W = Wc + which * 64 * EMB;

    const int tid  = threadIdx.x;
    const int wave = tid >> 6, lane = tid & 63;
    const int l16  = lane & 15, quad = lane >> 4;
    const int rs   = (wave & 1) * 16;        // row strip within block
    const int ch   = wave >> 1;              // col half: t in {2ch, 2ch+1}
    const int r0   = blockIdx.x * 32;
    const float* __restrict__ xb = x + (size_t)r0 * EMB;

    const int sr = tid >> 4;                 // 0..15 staging row base
    const int sc = (tid & 15) << 2;

    const f32x4 z = {0.f, 0.f, 0.f, 0.f};
    f32x4 acc[2] = {z, z};

    float4 xr[2];
    bf16x8 wf[4];

#define LOADX(dst, e0)                                                        \
    _Pragma("unroll")                                                         \
    for (int it = 0; it < 2; ++it)                                            \
        dst[it] = *(const float4*)(xb + (size_t)(it * 16 + sr) * EMB + (e0) + sc);

#define LOADW(dst, e0)                                                        \
    _Pragma("unroll")                                                         \
    for (int st = 0; st < 2; ++st)                                            \
        _Pragma("unroll")                                                     \
        for (int tt = 0; tt < 2; ++tt)                                        \
            dst[st * 2 + tt] = *(const bf16x8*)(W + (size_t)((ch * 2 + tt) * 16 + l16) * EMB \
                                                + (e0) + st * 32 + quad * 8);

    LOADX(xr, 0);
    LOADW(wf, 0);

    #pragma unroll
    for (int c = 0; c < 8; ++c) {
        const int e0 = c * 64;
        if (c) __syncthreads();
        #pragma unroll
        for (int it = 0; it < 2; ++it)
            *(ushort4*)&Xs[it * 16 + sr][sc] = cvt4(xr[it]);
        __syncthreads();

        bf16x8 a0 = *(const bf16x8*)&Xs[rs + l16][quad * 8];
        bf16x8 a1 = *(const bf16x8*)&Xs[rs + l16][32 + quad * 8];

        float4 xr2[2];
        bf16x8 wf2[4];
        if (c < 7) { LOADX(xr2, e0 + 64); LOADW(wf2, e0 + 64); }

        #pragma unroll
        for (int tt = 0; tt < 2; ++tt)
            acc[tt] = __builtin_amdgcn_mfma_f32_16x16x32_bf16(a0, wf[tt], acc[tt], 0, 0, 0);
        #pragma unroll
        for (int tt = 0; tt < 2; ++tt)
            acc[tt] = __builtin_amdgcn_mfma_f32_16x16x32_bf16(a1, wf[2 + tt], acc[tt], 0, 0, 0);

        if (c < 7) {
            #pragma unroll
            for (int it = 0; it < 2; ++it) xr[it] = xr2[it];
            #pragma unroll
            for (int j = 0; j < 4; ++j) wf[j] = wf2[j];
        }
    }
#undef LOADX
#undef LOADW

    #pragma unroll
    for (int tt = 0; tt < 2; ++tt) {
        #pragma unroll
        for (int r = 0; r < 4; ++r) {
            int row = r0 + rs + quad * 4 + r;
            int h   = (ch * 2 + tt) * 16 + l16;
            __hip_bfloat16 val = __float2bfloat16(acc[tt][r]);
            if (which == 0) {
                Qo[(size_t)row * HEAD + h] = val;   // already scaled via Wc
            } else if (which == 1) {
                Ko[(size_t)row * HEAD + h] = val;
            } else {
                int b = row >> 12, s = row & (SEQ - 1);
                Vto[((size_t)b * HEAD + h) * SEQ + s] = val;
            }
        }
    }
}

// ---------------------------------------------------------------------------
// Flash attention — R15 = R14 (verified async glds pipeline + full fence
// discipline) + T5 s_setprio around both MFMA clusters.
// Rationale: R14 counters show balanced-critical-path regime (MfmaUtil ~10%,
// VALUBusy ~13%, waves of the 4 independent blocks/CU sit at DIFFERENT
// phases). T5 pays exactly here (m191 attn +4-7%, m218b phase-split +21%,
// null only on lockstep m190): MFMA-cluster waves preempt staging/softmax
// waves at the SIMD arbiter. Zero correctness risk — additive only; all
// fences / vmcnt(4) / swizzle / barriers byte-identical to R14.
// ---------------------------------------------------------------------------
__global__ __launch_bounds__(256, 4) void attn_kernel(
    const __hip_bfloat16* __restrict__ Qb, const __hip_bfloat16* __restrict__ Kb,
    const __hip_bfloat16* __restrict__ Vt, float* __restrict__ Op,
    float* __restrict__ lp)
{
    __shared__ __hip_bfloat16 KsF[2][64][64];
    __shared__ __hip_bfloat16 VsF[2][64][64];   // V^T tile [d][kv]
    __shared__ __hip_bfloat16 PsF[64][64];      // 4 waves x 16 private rows

    const int tid  = threadIdx.x;
    const int wave = tid >> 6, lane = tid & 63;
    const int l16  = lane & 15, quad = lane >> 4;
    const int b    = blockIdx.y;
    const int q0   = blockIdx.x * 128;
    const int j0b  = blockIdx.z * (SEQ / NSPLIT);

    // Q B-frags direct from global: rows q0 + wave*32 + s*16 + l16
    bf16x8 qf[2][2];
    #pragma unroll
    for (int s = 0; s < 2; ++s) {
        const __hip_bfloat16* qrow =
            Qb + ((size_t)b * SEQ + q0 + wave * 32 + s * 16 + l16) * HEAD + quad * 8;
        qf[s][0] = *(const bf16x8*)(qrow);
        qf[s][1] = *(const bf16x8*)(qrow + 32);
    }

    // glds staging: wave w stages rows [w*16, w*16+16) of K and V tiles.
    // lane λ covers row (λ>>3) (+8 for it=1), 16B chunk (λ&7)^((λ>>3)&7)
    // (inverse swizzle on the SOURCE; LDS dest is linear base + λ*16).
    const int rl  = lane >> 3;                // 0..7
    const int ch8 = (lane & 7) ^ rl;          // swizzled 16B-chunk index
    const __hip_bfloat16* __restrict__ Ksrc0 =
        Kb + ((size_t)b * SEQ + wave * 16 + rl) * HEAD + ch8 * 8;
    const __hip_bfloat16* __restrict__ Vsrc0 =
        Vt + ((size_t)b * HEAD + wave * 16 + rl) * SEQ + ch8 * 8;

#define STAGE(bufi, j0)                                                       \
    do {                                                                      \
        _Pragma("unroll")                                                     \
        for (int it = 0; it < 2; ++it) {                                      \
            __builtin_amdgcn_global_load_lds(                                 \
                (const __attribute__((address_space(1))) unsigned int*)       \
                    (const void*)(Ksrc0 + ((size_t)(j0) + it * 8) * HEAD),    \
                (__attribute__((address_space(3))) unsigned int*)             \
                    (void*)&KsF[bufi][wave * 16 + it * 8][0], 16, 0, 0);      \
            __builtin_amdgcn_global_load_lds(                                 \
                (const __attribute__((address_space(1))) unsigned int*)       \
                    (const void*)(Vsrc0 + (j0) + (size_t)it * 8 * SEQ),       \
                (__attribute__((address_space(3))) unsigned int*)             \
                    (void*)&VsF[bufi][wave * 16 + it * 8][0], 16, 0, 0);      \
        }                                                                     \
    } while (0)

    const f32x4 z = {0.f, 0.f, 0.f, 0.f};
    f32x4 oacc[2][4] = {{z, z, z, z}, {z, z, z, z}};
    f32x4 lacc[2] = {z, z};

    const __hip_bfloat16 one_bf = __float2bfloat16(1.0f);
    bf16x8 ones;
    #pragma unroll
    for (int j = 0; j < 8; ++j) ones[j] = *(const __bf16*)&one_bf;

    STAGE(0, j0b);                            // prologue: tile 0 -> buf 0

    const int xs = l16 & 7;                   // read-side XOR (row&7)

    #pragma unroll
    for (int jt = 0; jt < SEQ / NSPLIT / 64; ++jt) {
        const int cur = jt & 1;
        if (jt < SEQ / NSPLIT / 64 - 1) {
            STAGE(cur ^ 1, j0b + (jt + 1) * 64);
            asm volatile("s_waitcnt vmcnt(4)" ::: "memory");
        } else {
            asm volatile("s_waitcnt vmcnt(0)" ::: "memory");
        }
        __builtin_amdgcn_sched_barrier(0);
        __builtin_amdgcn_s_barrier();
        // IR+machine fence: no LDS read of the fresh buffer may hoist above
        // the barrier (other waves' rows only guaranteed landed after it).
        asm volatile("" ::: "memory");

        #pragma unroll
        for (int s = 0; s < 2; ++s) {
            // S^T = K Q^T (swapped: lane holds S[k=16t+4*quad+r][q=l16])
            f32x4 sacc[4] = {z, z, z, z};
            __builtin_amdgcn_s_setprio(1);            // T5: MFMA cluster
            #pragma unroll
            for (int st = 0; st < 2; ++st)
                #pragma unroll
                for (int t = 0; t < 4; ++t) {
                    bf16x8 kf = *(const bf16x8*)
                        &KsF[cur][t * 16 + l16][((st * 4 + quad) ^ xs) * 8];
                    sacc[t] = __builtin_amdgcn_mfma_f32_16x16x32_bf16(kf, qf[s][st], sacc[t], 0, 0, 0);
                }
            __builtin_amdgcn_s_setprio(0);

            // Fence: prev strip's pf ds_reads stay BEFORE these ds_writes
            // (cross-lane WAR invisible to per-thread alias analysis).
            asm volatile("" ::: "memory");
            __builtin_amdgcn_sched_barrier(0);

            // p = exp2(s); pack 4 k-contiguous bf16 -> one swizzled 8B write
            #pragma unroll
            for (int t = 0; t < 4; ++t) {
                float4 p;
                p.x = __builtin_amdgcn_exp2f(sacc[t][0]);
                p.y = __builtin_amdgcn_exp2f(sacc[t][1]);
                p.z = __builtin_amdgcn_exp2f(sacc[t][2]);
                p.w = __builtin_amdgcn_exp2f(sacc[t][3]);
                *(ushort4*)&PsF[wave * 16 + l16]
                    [(((t * 2 + (quad >> 1)) ^ xs) * 8) + (quad & 1) * 4] = cvt4(p);
            }

            // Fence: the ds_writes stay BEFORE this strip's pf ds_reads
            // (cross-lane RAW; per-wave DS pipe executes in program order).
            asm volatile("" ::: "memory");
            __builtin_amdgcn_sched_barrier(0);

            // O += P V ; l += P * ones
            __builtin_amdgcn_s_setprio(1);            // T5: MFMA cluster
            #pragma unroll
            for (int st = 0; st < 2; ++st) {
                bf16x8 pf = *(const bf16x8*)
                    &PsF[wave * 16 + l16][((st * 4 + quad) ^ xs) * 8];
                lacc[s] = __builtin_amdgcn_mfma_f32_16x16x32_bf16(pf, ones, lacc[s], 0, 0, 0);
                #pragma unroll
                for (int t = 0; t < 4; ++t) {
                    bf16x8 vf = *(const bf16x8*)
                        &VsF[cur][t * 16 + l16][((st * 4 + quad) ^ xs) * 8];
                    oacc[s][t] = __builtin_amdgcn_mfma_f32_16x16x32_bf16(pf, vf, oacc[s][t], 0, 0, 0);
                }
            }
            __builtin_amdgcn_s_setprio(0);
        }
        // Drain this wave's DS reads BEFORE the end barrier so the next
        // iteration's glds cannot overwrite a buffer with reads pending
        // (compiler's own lgkm waits may have sunk past the barrier).
        asm volatile("s_waitcnt lgkmcnt(0)" ::: "memory");
        __builtin_amdgcn_sched_barrier(0);
        __builtin_amdgcn_s_barrier();
        asm volatile("" ::: "memory");   // STAGE may not hoist above barrier
    }
#undef STAGE

    // epilogue: disjoint fp32 partials
    const size_t pb = (size_t)(blockIdx.z * NB + b) * SEQ;
    #pragma unroll
    for (int s = 0; s < 2; ++s) {
        const size_t row0 = pb + q0 + wave * 32 + s * 16 + quad * 4;
        if (l16 == 0) {
            #pragma unroll
            for (int r = 0; r < 4; ++r)
                lp[row0 + r] = lacc[s][r];
        }
        #pragma unroll
        for (int t = 0; t < 4; ++t)
            #pragma unroll
            for (int r = 0; r < 4; ++r)
                Op[(row0 + r) * HEAD + t * 16 + l16] = oacc[s][t][r];
    }
}

// ---------------------------------------------------------------------------
// Merge: out = (sum_s O_s) / (sum_s l_s)
// ---------------------------------------------------------------------------
__global__ __launch_bounds__(256) void merge_kernel(
    const float* __restrict__ Op, const float* __restrict__ lp,
    float* __restrict__ out)
{
    int idx = blockIdx.x * 256 + threadIdx.x;   // [0, B*S*16)
    int bq  = idx >> 4;
    int c4  = (idx & 15) * 4;
    float4 acc = {0.f, 0.f, 0.f, 0.f};
    float  l   = 0.f;
    #pragma unroll
    for (int s = 0; s < NSPLIT; ++s) {
        float4 o = *(const float4*)(Op + ((size_t)s * NB * SEQ + bq) * HEAD + c4);
        acc.x += o.x; acc.y += o.y; acc.z += o.z; acc.w += o.w;
        l += lp[(size_t)s * NB * SEQ + bq];
    }
    float inv = 1.f / l;
    float4 r = {acc.x * inv, acc.y * inv, acc.z * inv, acc.w * inv};
    *(float4*)(out + (size_t)bq * HEAD + c4) = r;
}

extern "C" void kernel_launch(void* const* d_in, const int* in_sizes, int n_in,
                              void* d_out, int out_size, void* d_ws, size_t ws_size,
                              hipStream_t stream) {
    const float* q  = (const float*)d_in[0];
    const float* k  = (const float*)d_in[1];
    const float* v  = (const float*)d_in[2];
    const float* Wq = (const float*)d_in[3];
    const float* Wk = (const float*)d_in[4];
    const float* Wv = (const float*)d_in[5];
    float* out = (float*)d_out;

    // ws: Qb 2MB | Kb 2MB | Vt 2MB | Wc 192KB | Op 32MB | lp 512KB (~38.7MB)
    __hip_bfloat16* Qb = (__hip_bfloat16*)d_ws;
    __hip_bfloat16* Kb = Qb + (size_t)NB * SEQ * HEAD;
    __hip_bfloat16* Vt = Kb + (size_t)NB * SEQ * HEAD;
    __hip_bfloat16* Wc = Vt + (size_t)NB * SEQ * HEAD;
    float* Op = (float*)(Wc + 3 * 64 * EMB);
    float* lp = Op + (size_t)NSPLIT * NB * SEQ * HEAD;

    cvtw_kernel<<<96, 256, 0, stream>>>(Wq, Wk, Wv, Wc);

    dim3 pgrid(NB * SEQ / 32, 3);
    proj_kernel<<<pgrid, dim3(256), 0, stream>>>(q, k, v, Wc, Qb, Kb, Vt);

    dim3 agrid(SEQ / 128, NB, NSPLIT);
    attn_kernel<<<agrid, dim3(256), 0, stream>>>(Qb, Kb, Vt, Op, lp);

    merge_kernel<<<(NB * SEQ * 16) / 256, dim3(256), 0, stream>>>(Op, lp, out);
}